// Round 4
// baseline (1136.694 us; speedup 1.0000x reference)
//
#include <hip/hip_runtime.h>

// ---------------------------------------------------------------------------
// LabeledConv round 4: fully-fused aggregate+GEMM, direct-bucket CSR.
//   out = [Agg0(xb)|..|Agg3(xb)] @ [W'1;..;W'4] + epilogue
// Structure:
//   - scatter: per edge, rank = atomicAdd(hist) -> payload[idx*CAP+rank]=src
//     (overflow -> global list; expected empty for random graphs)
//   - fused kernel: 1 wave owns 16 output rows. Per edge-set s: aggregate its
//     16 nodes (lane = 4 channels) -> wave-private LDS tile (16x256 bf16,
//     padded), then MFMA tile @ Wt[:, s*256:+256] streamed from L2.
//     Agg intermediate never touches global memory; zero barriers.
//   - NT experiments of R3 reverted (payload reads are wave-uniform L1
//     broadcasts; NT forced them to memory -> R3 regression).
// ---------------------------------------------------------------------------

typedef __bf16 v8bf __attribute__((ext_vector_type(8)));
typedef float v4f __attribute__((ext_vector_type(4)));

__device__ __forceinline__ unsigned short f2bf(float f) {
  unsigned u = __float_as_uint(f);
  u += 0x7fffu + ((u >> 16) & 1u);  // RNE
  return (unsigned short)(u >> 16);
}
__device__ __forceinline__ float bf2f(unsigned short s) {
  return __uint_as_float(((unsigned)s) << 16);
}

// ---------------------------------------------------------------------------
// hist + direct bucket scatter (+ overflow list)
__global__ void lc_scatter(const int* __restrict__ e0, const int* __restrict__ e1,
                           const int* __restrict__ e2, const int* __restrict__ e3,
                           int* __restrict__ hist, int* __restrict__ payload,
                           int CAP, int* __restrict__ ovf_cnt, int2* __restrict__ ovf,
                           int N, int E) {
  int e = blockIdx.x * 256 + threadIdx.x;
  if (e >= E) return;
  int k = blockIdx.y;
  const int* ed = (k == 0) ? e0 : (k == 1) ? e1 : (k == 2) ? e2 : e3;
  int src = ed[e];
  int col = ed[E + e];
  int idx = k * N + col;
  int rank = atomicAdd(&hist[idx], 1);
  if (rank < CAP) {
    payload[(size_t)idx * CAP + rank] = src;
  } else {
    int o = atomicAdd(ovf_cnt, 1);
    ovf[o] = make_int2(idx, src);
  }
}

__global__ void lc_dis(const int* __restrict__ hist, float* __restrict__ dis, int M) {
  int i = blockIdx.x * 256 + threadIdx.x;
  if (i < M) dis[i] = rsqrtf((float)(hist[i] + 1));  // +1 self loop
}

__global__ void lc_bias(const float* __restrict__ b1, const float* __restrict__ b2,
                        const float* __restrict__ b3, const float* __restrict__ b4,
                        const float* __restrict__ p2, const float* __restrict__ p3,
                        const float* __restrict__ p4, const float* __restrict__ p5,
                        float* __restrict__ biasc) {
  int c = threadIdx.x;
  biasc[c] = b1[c] * p2[c] + b2[c] * p3[c] + b3[c] * p4[c] + b4[c] * p5[c];
}

// Wt[co][k*256+kk] = W_k[kk][co] * p_{k+2}[co]   (B^T layout: row=out col, K contiguous)
__global__ void lc_prep(const float* __restrict__ W1, const float* __restrict__ W2,
                        const float* __restrict__ W3, const float* __restrict__ W4,
                        const float* __restrict__ p2, const float* __restrict__ p3,
                        const float* __restrict__ p4, const float* __restrict__ p5,
                        unsigned short* __restrict__ Wt) {
  int b = blockIdx.x;
  int k = b >> 8, co = b & 255;
  int kk = threadIdx.x;
  const float* W = (k == 0) ? W1 : (k == 1) ? W2 : (k == 2) ? W3 : W4;
  const float* p = (k == 0) ? p2 : (k == 1) ? p3 : (k == 2) ? p4 : p5;
  Wt[(size_t)co * 1024 + k * 256 + kk] = f2bf(W[kk * 256 + co] * p[co]);
}

// x -> bf16; m0[n]=t0[n]*x[n,0], m1[n]=t1[n]*x[n,0]
__global__ void lc_cvt(const float4* __restrict__ x4, ushort4* __restrict__ xb4,
                       const float* __restrict__ t0, const float* __restrict__ t1,
                       float* __restrict__ m0, float* __restrict__ m1, int n4) {
  int i = blockIdx.x * 256 + threadIdx.x;
  if (i >= n4) return;
  float4 v = x4[i];
  ushort4 r;
  r.x = f2bf(v.x); r.y = f2bf(v.y); r.z = f2bf(v.z); r.w = f2bf(v.w);
  xb4[i] = r;
  if ((i & 63) == 0) {
    int n = i >> 6;
    float xc = v.x;
    m0[n] = t0[n] * xc;
    m1[n] = t1[n] * xc;
  }
}

// ---------------------------------------------------------------------------
// Fused aggregate+GEMM. Block = 256 thr = 4 waves; block owns 64 rows,
// wave w owns rows [blk*64 + w*16, +16). Wave-private LDS slice: 16 x 264
// bf16 (pad 8 to break bank alignment). No __syncthreads anywhere.
#define LROW 264
__global__ __launch_bounds__(256, 2) void lc_fused(
    const unsigned short* __restrict__ xb, const unsigned short* __restrict__ Wt,
    const int* __restrict__ payload, int CAP, const int* __restrict__ hist,
    const float* __restrict__ dis, const int* __restrict__ ovf_cnt,
    const int2* __restrict__ ovf, const float* __restrict__ m0,
    const float* __restrict__ m1, const float* __restrict__ p0,
    const float* __restrict__ p1, const float* __restrict__ biasc,
    float* __restrict__ out, int N) {
  __shared__ alignas(16) unsigned short lds[4 * 16 * LROW];
  int t = threadIdx.x;
  int w = t >> 6, lane = t & 63;
  int quad = lane >> 4, l16 = lane & 15;
  int row0 = blockIdx.x * 64 + w * 16;
  unsigned short* A = &lds[w * 16 * LROW];
  int c = lane * 4;

  v4f acc[16];
#pragma unroll
  for (int nt = 0; nt < 16; nt++) {
    v4f z = {0.f, 0.f, 0.f, 0.f};
    acc[nt] = z;
  }

  for (int s = 0; s < 4; s++) {
    // ---- aggregate 16 nodes for edge-set s into LDS tile ----
    for (int i = 0; i < 16; i++) {
      int node = row0 + i;
      if (node >= N) break;  // trailing rows: LDS garbage, stores guarded
      int idx = s * N + node;
      float dn = dis[idx];
      float sl = dn * dn;  // self-loop norm = 1/deg
      ushort4 hv = *(const ushort4*)&xb[(size_t)node * 256 + c];
      float a0 = bf2f(hv.x) * sl, a1 = bf2f(hv.y) * sl;
      float a2 = bf2f(hv.z) * sl, a3 = bf2f(hv.w) * sl;
      int cnt = hist[idx];
      int lim = cnt < CAP ? cnt : CAP;
      const int* pp = payload + (size_t)idx * CAP;
      int j = 0;
      for (; j + 4 <= lim; j += 4) {
        int s0 = pp[j], s1 = pp[j + 1], s2 = pp[j + 2], s3 = pp[j + 3];
        ushort4 g0 = *(const ushort4*)&xb[(size_t)s0 * 256 + c];
        ushort4 g1 = *(const ushort4*)&xb[(size_t)s1 * 256 + c];
        ushort4 g2 = *(const ushort4*)&xb[(size_t)s2 * 256 + c];
        ushort4 g3 = *(const ushort4*)&xb[(size_t)s3 * 256 + c];
        float n0 = dis[s * N + s0] * dn, n1 = dis[s * N + s1] * dn;
        float n2 = dis[s * N + s2] * dn, n3 = dis[s * N + s3] * dn;
        a0 += bf2f(g0.x) * n0 + bf2f(g1.x) * n1 + bf2f(g2.x) * n2 + bf2f(g3.x) * n3;
        a1 += bf2f(g0.y) * n0 + bf2f(g1.y) * n1 + bf2f(g2.y) * n2 + bf2f(g3.y) * n3;
        a2 += bf2f(g0.z) * n0 + bf2f(g1.z) * n1 + bf2f(g2.z) * n2 + bf2f(g3.z) * n3;
        a3 += bf2f(g0.w) * n0 + bf2f(g1.w) * n1 + bf2f(g2.w) * n2 + bf2f(g3.w) * n3;
      }
      for (; j < lim; j++) {
        int sj = pp[j];
        ushort4 g = *(const ushort4*)&xb[(size_t)sj * 256 + c];
        float nr = dis[s * N + sj] * dn;
        a0 += bf2f(g.x) * nr; a1 += bf2f(g.y) * nr;
        a2 += bf2f(g.z) * nr; a3 += bf2f(g.w) * nr;
      }
      if (cnt > CAP) {  // pathological-degree fallback (expected never)
        int tot = *ovf_cnt;
        for (int o = 0; o < tot; o++) {
          int2 ov = ovf[o];
          if (ov.x == idx) {
            int sj = ov.y;
            ushort4 g = *(const ushort4*)&xb[(size_t)sj * 256 + c];
            float nr = dis[s * N + sj] * dn;
            a0 += bf2f(g.x) * nr; a1 += bf2f(g.y) * nr;
            a2 += bf2f(g.z) * nr; a3 += bf2f(g.w) * nr;
          }
        }
      }
      ushort4 r;
      r.x = f2bf(a0); r.y = f2bf(a1); r.z = f2bf(a2); r.w = f2bf(a3);
      *(ushort4*)&A[i * LROW + c] = r;
    }
    // same-wave LDS ordering: ds ops complete in order per wave; no barrier.

    // ---- GEMM-accumulate: acc += A(16x256) @ Wt[:, s*256:+256]^T ----
#pragma unroll
    for (int kstep = 0; kstep < 8; kstep++) {
      v8bf af = *(const v8bf*)&A[l16 * LROW + kstep * 32 + quad * 8];
#pragma unroll
      for (int nt = 0; nt < 8; nt++) {
        int colb = nt * 16 + l16;
        v8bf bfr = *(const v8bf*)&Wt[(size_t)colb * 1024 + s * 256 + kstep * 32 + quad * 8];
        acc[nt] = __builtin_amdgcn_mfma_f32_16x16x32_bf16(af, bfr, acc[nt], 0, 0, 0);
      }
#pragma unroll
      for (int nt = 8; nt < 16; nt++) {
        int colb = nt * 16 + l16;
        v8bf bfr = *(const v8bf*)&Wt[(size_t)colb * 1024 + s * 256 + kstep * 32 + quad * 8];
        acc[nt] = __builtin_amdgcn_mfma_f32_16x16x32_bf16(af, bfr, acc[nt], 0, 0, 0);
      }
    }
  }

  // ---- epilogue: C/D layout col=l16, row=quad*4+reg ----
  float pc0[16], pc1[16], bc[16];
#pragma unroll
  for (int nt = 0; nt < 16; nt++) {
    int gcol = nt * 16 + l16;
    pc0[nt] = p0[gcol];
    pc1[nt] = p1[gcol];
    bc[nt] = biasc[gcol];
  }
#pragma unroll
  for (int r = 0; r < 4; r++) {
    int grow = row0 + quad * 4 + r;
    if (grow >= N) continue;
    float m0v = m0[grow], m1v = m1[grow];
#pragma unroll
    for (int nt = 0; nt < 16; nt++) {
      int gcol = nt * 16 + l16;
      out[(size_t)grow * 256 + gcol] =
          acc[nt][r] + m0v * pc0[nt] + m1v * pc1[nt] + bc[nt];
    }
  }
}

// ---------------------------------------------------------------------------
extern "C" void kernel_launch(void* const* d_in, const int* in_sizes, int n_in,
                              void* d_out, int out_size, void* d_ws, size_t ws_size,
                              hipStream_t stream) {
  const float* x = (const float*)d_in[0];
  const int* e00 = (const int*)d_in[1];
  const int* e01 = (const int*)d_in[2];
  const int* e10 = (const int*)d_in[3];
  const int* e11 = (const int*)d_in[4];
  const float* t0 = (const float*)d_in[5];
  const float* t1 = (const float*)d_in[6];
  const float* W1 = (const float*)d_in[7];
  const float* b1 = (const float*)d_in[8];
  const float* W2 = (const float*)d_in[9];
  const float* b2 = (const float*)d_in[10];
  const float* W3 = (const float*)d_in[11];
  const float* b3 = (const float*)d_in[12];
  const float* W4 = (const float*)d_in[13];
  const float* b4 = (const float*)d_in[14];
  const float* p0 = (const float*)d_in[15];
  const float* p1 = (const float*)d_in[16];
  const float* p2 = (const float*)d_in[17];
  const float* p3 = (const float*)d_in[18];
  const float* p4 = (const float*)d_in[19];
  const float* p5 = (const float*)d_in[20];
  float* out = (float*)d_out;

  int N = in_sizes[0] / 256;
  int E = in_sizes[1] / 2;
  int M4 = 4 * N;

  char* wp = (char*)d_ws;
  auto carve = [&](size_t bytes) {
    void* r = (void*)wp;
    wp += (bytes + 255) & ~(size_t)255;
    return r;
  };
  unsigned short* xb = (unsigned short*)carve((size_t)N * 256 * 2);
  unsigned short* Wt = (unsigned short*)carve((size_t)256 * 1024 * 2);
  int* hist = (int*)carve((size_t)(M4 + 1) * 4);  // +1: ovf_cnt rides along
  int* ovf_cnt = hist + M4;
  float* dis = (float*)carve((size_t)M4 * 4);
  float* biasc = (float*)carve(256 * 4);
  float* m0 = (float*)carve((size_t)N * 4);
  float* m1 = (float*)carve((size_t)N * 4);
  int2* ovf = (int2*)carve((size_t)E * 8);  // worst-case overflow capacity
  size_t used = (size_t)(wp - (char*)d_ws);
  size_t remain = (ws_size > used) ? ws_size - used : 0;
  // bucket capacity: prefer 64 slots/node, shrink if workspace is tight
  int CAP = 64;
  while (CAP > 4 && remain < (size_t)M4 * CAP * 4) CAP >>= 1;
  int* payload = (int*)wp;

  int gE = (E + 255) / 256;
  int gM = (M4 + 255) / 256;

  hipMemsetAsync(hist, 0, (size_t)(M4 + 1) * 4, stream);
  lc_scatter<<<dim3(gE, 4), 256, 0, stream>>>(e00, e01, e10, e11, hist, payload,
                                              CAP, ovf_cnt, ovf, N, E);
  lc_dis<<<gM, 256, 0, stream>>>(hist, dis, M4);
  lc_bias<<<1, 256, 0, stream>>>(b1, b2, b3, b4, p2, p3, p4, p5, biasc);
  lc_prep<<<1024, 256, 0, stream>>>(W1, W2, W3, W4, p2, p3, p4, p5, Wt);
  lc_cvt<<<(N * 64 + 255) / 256, 256, 0, stream>>>((const float4*)x, (ushort4*)xb,
                                                   t0, t1, m0, m1, N * 64);
  lc_fused<<<(N + 63) / 64, 256, 0, stream>>>(xb, Wt, payload, CAP, hist, dis,
                                              ovf_cnt, ovf, m0, m1, p0, p1, biasc,
                                              out, N);
}